// Round 1
// baseline (1725.998 us; speedup 1.0000x reference)
//
#include <hip/hip_runtime.h>
#include <math.h>

#define DIM   3072
#define TEMB_ 512
#define NB    2
#define TTXT  226
#define SVID  1024
#define SEQ   1250
#define MTOT  2500
#define MPAD  2560
#define FFD   12288
#define NH    48
#define HD_   64

typedef __attribute__((ext_vector_type(8))) short bh8;
typedef __attribute__((ext_vector_type(4))) short bh4;
typedef __attribute__((ext_vector_type(4))) float f32x4;

__device__ __forceinline__ float b2f(short u){
  union { float f; unsigned i; } x; x.i = ((unsigned)(unsigned short)u) << 16; return x.f;
}
__device__ __forceinline__ short f2b(float f){
  union { float f; unsigned i; } x; x.f = f;
  unsigned r = x.i + 0x7fffu + ((x.i >> 16) & 1u);   // RNE
  return (short)(r >> 16);
}
__device__ __forceinline__ float gelu_t(float x){
  float t = tanhf(0.7978845608028654f*(x + 0.044715f*x*x*x));
  return 0.5f*x*(1.0f + t);
}
// XOR-swizzled LDS byte address (T2-style, 16B granule), consistent read/write
__device__ __forceinline__ void* swzp(void* base, int row, int byteoff, int rowstride){
  int b = row*rowstride + byteoff;
  b ^= (row & 7) << 4;
  return (void*)((char*)base + b);
}

// ---------------- adaLN modulation vectors: mods = silu(temb) @ W.T + b ------
__global__ __launch_bounds__(256) void adaln_mods_k(
    const float* __restrict__ temb,
    const float* __restrict__ W1, const float* __restrict__ B1,
    const float* __restrict__ W2, const float* __restrict__ B2,
    float* __restrict__ mo1, float* __restrict__ mo2)
{
  const int b = blockIdx.y, set = blockIdx.z;
  const float* W  = set ? W2 : W1;
  const float* Bv = set ? B2 : B1;
  float* mo = set ? mo2 : mo1;
  __shared__ float st[TEMB_];
  const int tid = threadIdx.x;
  for (int i = tid; i < TEMB_; i += 256){
    float t = temb[b*TEMB_ + i];
    st[i] = t / (1.0f + __expf(-t));
  }
  __syncthreads();
  const int col = blockIdx.x*256 + tid;
  const float* wr = W + (size_t)col*TEMB_;
  float acc = 0.f;
  #pragma unroll 4
  for (int k2 = 0; k2 < TEMB_; k2 += 4){
    const float4 w4 = *(const float4*)(wr + k2);
    acc += st[k2]*w4.x + st[k2+1]*w4.y + st[k2+2]*w4.z + st[k2+3]*w4.w;
  }
  mo[b*6*DIM + col] = acc + Bv[col];
}

// ---------------- fp32 -> bf16 weight cast -----------------------------------
__global__ __launch_bounds__(256) void cvt_f2b_k(const float* __restrict__ s,
                                                 short* __restrict__ d, int n4)
{
  int i = blockIdx.x*256 + threadIdx.x;
  if (i >= n4) return;
  const float4 v = *(const float4*)(s + (size_t)i*4);
  bh4 o = { f2b(v.x), f2b(v.y), f2b(v.z), f2b(v.w) };
  *(bh4*)(d + (size_t)i*4) = o;
}

// ---------------- LayerNorm + adaLN modulate -> bf16 cat ---------------------
// SRC=0: read from (enc | hidden) inputs; SRC=1: read from resid (cat order)
template<int SRC>
__global__ __launch_bounds__(256) void ln_mod_k(
    const float* __restrict__ hidden, const float* __restrict__ enc,
    const float* __restrict__ residf, const float* __restrict__ mods,
    const float* __restrict__ g, const float* __restrict__ bv,
    short* __restrict__ outc)
{
  const int m = blockIdx.x, tid = threadIdx.x;
  if (m >= MTOT){                      // zero pad rows 2500..2559
    bh8 z = {};
    for (int c = tid*8; c < DIM; c += 2048) *(bh8*)&outc[(size_t)m*DIM + c] = z;
    return;
  }
  const int b = m / SEQ, s = m - b*SEQ;
  const float* src;
  if (SRC == 1) src = residf + (size_t)m*DIM;
  else src = (s < TTXT) ? enc + ((size_t)(b*TTXT + s))*DIM
                        : hidden + ((size_t)(b*SVID + (s - TTXT)))*DIM;
  float4 vb[3];
  float sum = 0.f, sq = 0.f;
  #pragma unroll
  for (int i = 0; i < 3; i++){
    vb[i] = *(const float4*)(src + tid*4 + i*1024);
    sum += vb[i].x + vb[i].y + vb[i].z + vb[i].w;
    sq  += vb[i].x*vb[i].x + vb[i].y*vb[i].y + vb[i].z*vb[i].z + vb[i].w*vb[i].w;
  }
  #pragma unroll
  for (int d = 1; d < 64; d <<= 1){ sum += __shfl_xor(sum, d); sq += __shfl_xor(sq, d); }
  __shared__ float red[8];
  if ((tid & 63) == 0){ red[tid>>6] = sum; red[4 + (tid>>6)] = sq; }
  __syncthreads();
  sum = red[0]+red[1]+red[2]+red[3];
  sq  = red[4]+red[5]+red[6]+red[7];
  const float mean = sum * (1.0f/DIM);
  const float inv  = rsqrtf(sq*(1.0f/DIM) - mean*mean + 1e-5f);
  const int mo = b*6*DIM + ((s < TTXT) ? 3*DIM : 0);   // (esh,esc) vs (sh,sc)
  #pragma unroll
  for (int i = 0; i < 3; i++){
    const int c = tid*4 + i*1024;
    const float vv[4] = {vb[i].x, vb[i].y, vb[i].z, vb[i].w};
    bh4 o;
    #pragma unroll
    for (int j = 0; j < 4; j++){
      float y = (vv[j] - mean)*inv*g[c+j] + bv[c+j];
      y = y*(1.0f + mods[mo + DIM + c + j]) + mods[mo + c + j];
      o[j] = f2b(y);
    }
    *(bh4*)&outc[(size_t)m*DIM + c] = o;
  }
}

// ---------------- bf16 MFMA GEMM: C[m][n] = sum_k A[m][k]*W[n][k] ------------
#define EPI_QKV   0
#define EPI_OPROJ 1
#define EPI_FF1   2
#define EPI_FF2   3

template<int EPI>
__global__ __launch_bounds__(256, 2) void gemm_bt_k(
    const short* __restrict__ A, const short* __restrict__ Wb,
    const int M, const int N, const int K,
    short* __restrict__ Cb, float* __restrict__ Cf,
    const float* __restrict__ bias,
    const float* __restrict__ resid, const float* __restrict__ mods,
    float* __restrict__ outp)
{
  __shared__ short smA[128*32];
  __shared__ short smB[128*32];
  const int tid = threadIdx.x;
  const int wid = tid >> 6, lane = tid & 63, lhi = lane >> 4, llo = lane & 15;
  const int m0 = blockIdx.y*128, n0 = blockIdx.x*128;
  const short* Wz = Wb;
  short* Cz = Cb;
  if constexpr (EPI == EPI_QKV){
    Wz += (size_t)blockIdx.z * N * K;
    Cz += (size_t)blockIdx.z * MPAD * N;
  }
  const int wr = (wid >> 1)*64, wc = (wid & 1)*64;
  f32x4 acc[4][4] = {};
  const int sr = tid >> 2;          // staging row 0..63
  const int so = (tid & 3)*16;      // staging byte offset in row
  for (int k0 = 0; k0 < K; k0 += 32){
    const bh8 a0 = *(const bh8*)(A  + (size_t)(m0 + sr)*K      + k0 + (so >> 1));
    const bh8 a1 = *(const bh8*)(A  + (size_t)(m0 + 64 + sr)*K + k0 + (so >> 1));
    const bh8 b0 = *(const bh8*)(Wz + (size_t)(n0 + sr)*K      + k0 + (so >> 1));
    const bh8 b1 = *(const bh8*)(Wz + (size_t)(n0 + 64 + sr)*K + k0 + (so >> 1));
    __syncthreads();
    *(bh8*)swzp(smA, sr,      so, 64) = a0;
    *(bh8*)swzp(smA, 64 + sr, so, 64) = a1;
    *(bh8*)swzp(smB, sr,      so, 64) = b0;
    *(bh8*)swzp(smB, 64 + sr, so, 64) = b1;
    __syncthreads();
    bh8 af[4], bf[4];
    #pragma unroll
    for (int i = 0; i < 4; i++) af[i] = *(const bh8*)swzp(smA, wr + i*16 + llo, lhi*16, 64);
    #pragma unroll
    for (int i = 0; i < 4; i++) bf[i] = *(const bh8*)swzp(smB, wc + i*16 + llo, lhi*16, 64);
    #pragma unroll
    for (int i = 0; i < 4; i++)
      #pragma unroll
      for (int j = 0; j < 4; j++)
        acc[i][j] = __builtin_amdgcn_mfma_f32_16x16x32_bf16(af[i], bf[j], acc[i][j], 0, 0, 0);
  }
  #pragma unroll
  for (int i = 0; i < 4; i++){
    #pragma unroll
    for (int j = 0; j < 4; j++){
      const int col = n0 + wc + j*16 + llo;
      #pragma unroll
      for (int r = 0; r < 4; r++){
        const int row = m0 + wr + i*16 + lhi*4 + r;
        if (row >= M) continue;
        const float v = acc[i][j][r];
        if constexpr (EPI == EPI_QKV){
          Cz[(size_t)row*N + col] = f2b(v);
        } else if constexpr (EPI == EPI_OPROJ){
          Cf[(size_t)row*N + col] = v + bias[col];
        } else if constexpr (EPI == EPI_FF1){
          Cz[(size_t)row*N + col] = f2b(gelu_t(v + bias[col]));
        } else {
          const float val = v + bias[col];
          const int b = row / SEQ, s = row - (row/SEQ)*SEQ;
          const float rv = resid[(size_t)row*DIM + col];
          if (s < TTXT){
            const float gg = mods[b*6*DIM + 5*DIM + col];   // egff
            outp[(size_t)NB*SVID*DIM + ((size_t)(b*TTXT + s))*DIM + col] = rv + gg*val;
          } else {
            const float gg = mods[b*6*DIM + 2*DIM + col];   // gff
            outp[((size_t)(b*SVID + (s - TTXT)))*DIM + col] = rv + gg*val;
          }
        }
      }
    }
  }
}

// ---------------- per-head LN (HD=64) + RoPE, in-place on bf16 q,k -----------
__global__ __launch_bounds__(256) void qk_ln_rope_k(
    short* __restrict__ q, short* __restrict__ k,
    const float* __restrict__ nqg, const float* __restrict__ nqb,
    const float* __restrict__ nkg, const float* __restrict__ nkb,
    const float* __restrict__ rc, const float* __restrict__ rs)
{
  const int tid = threadIdx.x, lane = tid & 63;
  const int idx = blockIdx.x*4 + (tid >> 6);
  const int m = idx / NH, h = idx - (idx/NH)*NH;
  if (m >= MTOT) return;
  const size_t base = (size_t)m*DIM + h*HD_ + lane;
  const int s = m % SEQ;
  const bool dorope = (s >= TTXT);
  float cv = 0.f, sv = 0.f;
  if (dorope){ const int p = s - TTXT; cv = rc[p*HD_ + lane]; sv = rs[p*HD_ + lane]; }
  {
    const float x = b2f(q[base]);
    float mu = x, ms = x*x;
    #pragma unroll
    for (int d = 1; d < 64; d <<= 1){ mu += __shfl_xor(mu, d); ms += __shfl_xor(ms, d); }
    mu *= (1.f/64.f); ms *= (1.f/64.f);
    float y = (x - mu)*rsqrtf(ms - mu*mu + 1e-6f)*nqg[lane] + nqb[lane];
    if (dorope){ const float pt = __shfl_xor(y, 1); y = y*cv + ((lane & 1) ? pt : -pt)*sv; }
    q[base] = f2b(y);
  }
  {
    const float x = b2f(k[base]);
    float mu = x, ms = x*x;
    #pragma unroll
    for (int d = 1; d < 64; d <<= 1){ mu += __shfl_xor(mu, d); ms += __shfl_xor(ms, d); }
    mu *= (1.f/64.f); ms *= (1.f/64.f);
    float y = (x - mu)*rsqrtf(ms - mu*mu + 1e-6f)*nkg[lane] + nkb[lane];
    if (dorope){ const float pt = __shfl_xor(y, 1); y = y*cv + ((lane & 1) ? pt : -pt)*sv; }
    k[base] = f2b(y);
  }
}

// ---------------- flash attention, 64 q-rows/block, 32-wide K/V tiles --------
__global__ __launch_bounds__(256, 2) void attn_k(
    const short* __restrict__ q, const short* __restrict__ k,
    const short* __restrict__ v, short* __restrict__ o)
{
  __shared__ short smK[32*64];
  __shared__ short smVT[64*32];
  __shared__ short smP[4*16*32];
  const int tid = threadIdx.x, wid = tid >> 6, lane = tid & 63, lhi = lane >> 4, llo = lane & 15;
  const int q0 = blockIdx.x*64, h = blockIdx.y, b = blockIdx.z;
  const size_t hb = (size_t)b*SEQ*DIM + h*HD_;
  bh8 qf0, qf1;
  {
    const int qr = q0 + wid*16 + llo;      // may be junk past 1250; store-guarded
    const short* p = q + hb + (size_t)qr*DIM + lhi*8;
    qf0 = *(const bh8*)p;
    qf1 = *(const bh8*)(p + 32);
  }
  f32x4 of[4] = {};
  float mrun[4], lrun[4];
  #pragma unroll
  for (int r = 0; r < 4; r++){ mrun[r] = -1e30f; lrun[r] = 0.f; }
  const int skr = tid >> 3, sko = (tid & 7)*16;
  for (int kt = 0; kt < (SEQ + 31)/32; kt++){
    const int k0 = kt*32;
    __syncthreads();
    {
      const bh8 kv = *(const bh8*)(k + hb + (size_t)(k0 + skr)*DIM + (sko >> 1));
      *(bh8*)swzp(smK, skr, sko, 128) = kv;
      const bh8 vv = *(const bh8*)(v + hb + (size_t)(k0 + skr)*DIM + (sko >> 1));
      #pragma unroll
      for (int j = 0; j < 8; j++)
        *(short*)swzp(smVT, (sko >> 1) + j, skr*2, 64) = vv[j];   // transposed V
    }
    __syncthreads();
    float ps[2][4], mx[4];
    #pragma unroll
    for (int ni = 0; ni < 2; ni++){
      f32x4 z = {0.f, 0.f, 0.f, 0.f};
      const bh8 kf0 = *(const bh8*)swzp(smK, ni*16 + llo, lhi*16, 128);
      const bh8 kf1 = *(const bh8*)swzp(smK, ni*16 + llo, 64 + lhi*16, 128);
      z = __builtin_amdgcn_mfma_f32_16x16x32_bf16(qf0, kf0, z, 0, 0, 0);
      z = __builtin_amdgcn_mfma_f32_16x16x32_bf16(qf1, kf1, z, 0, 0, 0);
      const bool inval = (k0 + ni*16 + llo >= SEQ);
      #pragma unroll
      for (int r = 0; r < 4; r++)
        ps[ni][r] = inval ? -1e30f : z[r]*0.125f;
    }
    #pragma unroll
    for (int r = 0; r < 4; r++) mx[r] = fmaxf(ps[0][r], ps[1][r]);
    #pragma unroll
    for (int d = 1; d < 16; d <<= 1)
      #pragma unroll
      for (int r = 0; r < 4; r++) mx[r] = fmaxf(mx[r], __shfl_xor(mx[r], d));
    float alpha[4], rsum[4];
    #pragma unroll
    for (int r = 0; r < 4; r++){
      const float mn = fmaxf(mrun[r], mx[r]);
      alpha[r] = __expf(mrun[r] - mn);
      mrun[r] = mn;
      const float p0 = __expf(ps[0][r] - mn);
      const float p1 = __expf(ps[1][r] - mn);
      ps[0][r] = p0; ps[1][r] = p1;
      rsum[r] = p0 + p1;
    }
    #pragma unroll
    for (int d = 1; d < 16; d <<= 1)
      #pragma unroll
      for (int r = 0; r < 4; r++) rsum[r] += __shfl_xor(rsum[r], d);
    short* myP = &smP[wid*512];            // wave-private: no barrier needed
    #pragma unroll
    for (int r = 0; r < 4; r++){
      lrun[r] = lrun[r]*alpha[r] + rsum[r];
      #pragma unroll
      for (int nd = 0; nd < 4; nd++) of[nd][r] *= alpha[r];
      *(short*)swzp(myP, lhi*4 + r, llo*2, 64)        = f2b(ps[0][r]);
      *(short*)swzp(myP, lhi*4 + r, (16 + llo)*2, 64) = f2b(ps[1][r]);
    }
    const bh8 pf = *(const bh8*)swzp(myP, llo, lhi*16, 64);
    #pragma unroll
    for (int nd = 0; nd < 4; nd++){
      const bh8 vf = *(const bh8*)swzp(smVT, nd*16 + llo, lhi*16, 64);
      of[nd] = __builtin_amdgcn_mfma_f32_16x16x32_bf16(pf, vf, of[nd], 0, 0, 0);
    }
  }
  #pragma unroll
  for (int r = 0; r < 4; r++){
    const int qr = q0 + wid*16 + lhi*4 + r;
    if (qr < SEQ){
      const float inv = 1.f/lrun[r];
      #pragma unroll
      for (int nd = 0; nd < 4; nd++)
        o[hb + (size_t)qr*DIM + nd*16 + llo] = f2b(of[nd][r]*inv);
    }
  }
}

// ---------------- attn residual: resid = base + gate * oproj -----------------
__global__ __launch_bounds__(256) void resid1_k(
    const float* __restrict__ hidden, const float* __restrict__ enc,
    const float* __restrict__ opj, const float* __restrict__ mods,
    float* __restrict__ resid)
{
  const size_t i4 = ((size_t)blockIdx.x*256 + threadIdx.x)*4;
  const int m = (int)(i4 / DIM), c = (int)(i4 - (size_t)m*DIM);
  const int b = m / SEQ, s = m - b*SEQ;
  const float* bp; const float* gp;
  if (s < TTXT){ bp = enc + ((size_t)(b*TTXT + s))*DIM + c;           gp = mods + b*6*DIM + 5*DIM + c; }
  else         { bp = hidden + ((size_t)(b*SVID + s - TTXT))*DIM + c; gp = mods + b*6*DIM + 2*DIM + c; }
  const float4 ov = *(const float4*)(opj + i4);
  const float4 bb = *(const float4*)bp;
  const float4 gg = *(const float4*)gp;
  float4 rr;
  rr.x = bb.x + gg.x*ov.x; rr.y = bb.y + gg.y*ov.y;
  rr.z = bb.z + gg.z*ov.z; rr.w = bb.w + gg.w*ov.w;
  *(float4*)(resid + i4) = rr;
}

// ---------------- launcher ---------------------------------------------------
extern "C" void kernel_launch(void* const* d_in, const int* in_sizes, int n_in,
                              void* d_out, int out_size, void* d_ws, size_t ws_size,
                              hipStream_t stream)
{
  (void)in_sizes; (void)n_in; (void)out_size; (void)ws_size;
  const float* hidden = (const float*)d_in[0];
  const float* enc    = (const float*)d_in[1];
  const float* temb   = (const float*)d_in[2];
  const float* ropec  = (const float*)d_in[3];
  const float* ropes  = (const float*)d_in[4];
  const float* w_ad1  = (const float*)d_in[5];
  const float* b_ad1  = (const float*)d_in[6];
  const float* ln1g   = (const float*)d_in[7];
  const float* ln1b   = (const float*)d_in[8];
  const float* wq     = (const float*)d_in[9];
  const float* wk     = (const float*)d_in[10];
  const float* wv     = (const float*)d_in[11];
  const float* wo     = (const float*)d_in[12];
  const float* bo     = (const float*)d_in[13];
  const float* nqg    = (const float*)d_in[14];
  const float* nqb    = (const float*)d_in[15];
  const float* nkg    = (const float*)d_in[16];
  const float* nkb    = (const float*)d_in[17];
  const float* w_ad2  = (const float*)d_in[18];
  const float* b_ad2  = (const float*)d_in[19];
  const float* ln2g   = (const float*)d_in[20];
  const float* ln2b   = (const float*)d_in[21];
  const float* wff1   = (const float*)d_in[22];
  const float* bff1   = (const float*)d_in[23];
  const float* wff2   = (const float*)d_in[24];
  const float* bff2   = (const float*)d_in[25];
  float* outp = (float*)d_out;

  char* ws = (char*)d_ws;
  size_t off = 0;
  auto alloc = [&](size_t bytes)->char*{
    char* p = ws + off; off += (bytes + 255) & ~(size_t)255; return p;
  };
  short* wqkv_b = (short*)alloc((size_t)3*DIM*DIM*2);
  short* wo_b   = (short*)alloc((size_t)DIM*DIM*2);
  short* wf1_b  = (short*)alloc((size_t)FFD*DIM*2);
  short* wf2_b  = (short*)alloc((size_t)FFD*DIM*2);
  short* regA   = (short*)alloc((size_t)MPAD*DIM*2);   // cat1, later attn-out
  short* regB   = (short*)alloc((size_t)MPAD*FFD*2);   // q,k,v ; later ff1
  float* regC   = (float*)alloc((size_t)MPAD*DIM*4);   // oproj ; later cat2(bf16)
  float* residf = (float*)alloc((size_t)MPAD*DIM*4);
  float* mods1  = (float*)alloc((size_t)NB*6*DIM*4);
  float* mods2  = (float*)alloc((size_t)NB*6*DIM*4);

  short* q_rm = regB;
  short* k_rm = regB + (size_t)MPAD*DIM;
  short* v_rm = regB + (size_t)2*MPAD*DIM;
  short* o_rm = regA;
  short* cat2 = (short*)regC;

  adaln_mods_k<<<dim3(6*DIM/256, NB, 2), 256, 0, stream>>>(temb, w_ad1, b_ad1, w_ad2, b_ad2, mods1, mods2);
  cvt_f2b_k<<<dim3(DIM*DIM/1024), 256, 0, stream>>>(wq, wqkv_b, DIM*DIM/4);
  cvt_f2b_k<<<dim3(DIM*DIM/1024), 256, 0, stream>>>(wk, wqkv_b + (size_t)DIM*DIM, DIM*DIM/4);
  cvt_f2b_k<<<dim3(DIM*DIM/1024), 256, 0, stream>>>(wv, wqkv_b + (size_t)2*DIM*DIM, DIM*DIM/4);
  cvt_f2b_k<<<dim3(DIM*DIM/1024), 256, 0, stream>>>(wo, wo_b, DIM*DIM/4);
  cvt_f2b_k<<<dim3(FFD*DIM/1024), 256, 0, stream>>>(wff1, wf1_b, FFD*DIM/4);
  cvt_f2b_k<<<dim3(FFD*DIM/1024), 256, 0, stream>>>(wff2, wf2_b, FFD*DIM/4);

  ln_mod_k<0><<<dim3(MPAD), 256, 0, stream>>>(hidden, enc, nullptr, mods1, ln1g, ln1b, regA);

  gemm_bt_k<EPI_QKV><<<dim3(DIM/128, MPAD/128, 3), 256, 0, stream>>>(
      regA, wqkv_b, MTOT, DIM, DIM, regB, nullptr, nullptr, nullptr, nullptr, nullptr);

  qk_ln_rope_k<<<dim3(MTOT*NH/4), 256, 0, stream>>>(q_rm, k_rm, nqg, nqb, nkg, nkb, ropec, ropes);

  attn_k<<<dim3((SEQ + 63)/64, NH, NB), 256, 0, stream>>>(q_rm, k_rm, v_rm, o_rm);

  gemm_bt_k<EPI_OPROJ><<<dim3(DIM/128, MPAD/128, 1), 256, 0, stream>>>(
      o_rm, wo_b, MTOT, DIM, DIM, nullptr, regC, bo, nullptr, nullptr, nullptr);

  resid1_k<<<dim3(MTOT*DIM/1024), 256, 0, stream>>>(hidden, enc, regC, mods1, residf);

  ln_mod_k<1><<<dim3(MPAD), 256, 0, stream>>>(nullptr, nullptr, residf, mods2, ln2g, ln2b, cat2);

  gemm_bt_k<EPI_FF1><<<dim3(FFD/128, MPAD/128, 1), 256, 0, stream>>>(
      cat2, wf1_b, MTOT, FFD, DIM, regB, nullptr, bff1, nullptr, nullptr, nullptr);

  gemm_bt_k<EPI_FF2><<<dim3(DIM/128, MPAD/128, 1), 256, 0, stream>>>(
      regB, wf2_b, MTOT, DIM, FFD, nullptr, nullptr, bff2, residf, mods2, outp);
}